// Round 9
// baseline (223.374 us; speedup 1.0000x reference)
//
#include <hip/hip_runtime.h>
#include <cstdint>
#include <cstddef>

// ---------------------------------------------------------------------------
// MultiHeadAttention forward, MI355X/gfx950.
// cvt(fp32->bf16) -> fused QKV GEMM (MFMA) -> flash attention -> out-proj.
// MFMA layouts (m89/m91/m120):
//   K=32 A-frag: lane l holds A[m=l&15][k=(l>>4)*8+j], j=0..7
//   K=32 B-frag: lane l holds Bt[n=l&15][k=(l>>4)*8+j]
//   C/D: lane l, reg r holds D[m=(l>>4)*4+r][n=l&15]
// R15: R14's PV/SM overlap WITHOUT the KVBLK confound. R14b (KVBLK 64,
// 32 barriers, offset pipeline) regressed 53.9->61.4: doubling the
// full-drain barrier count at 2 waves/SIMD cost more than the overlap
// gained (MfmaUtil AND VALUBusy both fell). R15 keeps R13's geometry
// exactly (KVBLK=128, 2 LDS buffers, 16 barriers) and carries tile t-1's
// V-fragments (vreg[4][4] bf16x8, 64 VGPR) and P (pk, 32 VGPR) in
// REGISTERS across the iteration boundary:
//   iter t: barrier; stage(t+1); QK(t); PV(t-1) from regs; SM(t); VLOAD(t)
// PV(t-1)'s 40 MFMAs have no data dependence on QK(t)/SM(t) -> they fill
// the matrix pipe while SM's exp2/cvt chain runs on the VALU (same-wave
// dual-pipe issue). Online softmax exact: SM(t)'s rescale touches Oacc
// after PV(t-1) accumulated (source order + data dep). Buffer safety
// unchanged from R13 (all buf reads of tile t-1 complete in iter t-1).
// Kept: 4 waves x 32 q (2 groups of 16) sharing K LDS reads, XCD swizzle,
// XOR-swizzled unpadded K/V LDS, ones-MFMA Racc rowsum, K=32 PV, max3-tree
// rmax, defer-max THR=8, exp2 domain (QSCALE folded), separate cvt7 (R12
// falsified fusion), single-buffered projection GEMMs (R11 falsified dbuf).
// ---------------------------------------------------------------------------

#define D_MODEL 1024
#define NHEAD   16
#define HDIM    64
#define BATCH   2
#define SEQ     2048
#define BT      (BATCH * SEQ)   // 4096

// (1/sqrt(HDIM)) * log2(e) -- folds softmax scale + exp->exp2 conversion
#define QSCALE 0.18033688011112043f

typedef __bf16 bf16;
typedef __bf16 bf16x8 __attribute__((ext_vector_type(8)));
typedef __bf16 bf16x4 __attribute__((ext_vector_type(4)));
typedef float  floatx4 __attribute__((ext_vector_type(4)));
typedef short  short4v __attribute__((ext_vector_type(4)));

#define MFMA16(a, b, c) __builtin_amdgcn_mfma_f32_16x16x32_bf16((a), (b), (c), 0, 0, 0)

__device__ __forceinline__ float fexp2(float x) {
  return __builtin_amdgcn_exp2f(x);   // v_exp_f32: D = 2^S0
}

// async global->LDS, 16B per lane. LDS dest = wave-uniform base + lane*16.
__device__ __forceinline__ void async_cp16(const bf16* g, bf16* l) {
  __builtin_amdgcn_global_load_lds(
      (__attribute__((address_space(1))) void*)(g),
      (__attribute__((address_space(3))) void*)(l), 16, 0, 0);
}

// ---------------------------------------------------------------------------
// fp32 -> bf16 conversion for q,k,v and the 4 weight matrices.
// ---------------------------------------------------------------------------
__global__ __launch_bounds__(256) void cvt7(
    const float* __restrict__ s0, const float* __restrict__ s1,
    const float* __restrict__ s2, const float* __restrict__ s3,
    const float* __restrict__ s4, const float* __restrict__ s5,
    const float* __restrict__ s6,
    bf16* __restrict__ d0, bf16* __restrict__ d1, bf16* __restrict__ d2,
    bf16* __restrict__ d3, bf16* __restrict__ d4, bf16* __restrict__ d5,
    bf16* __restrict__ d6)
{
  const float* src; bf16* dst; int n4;
  switch (blockIdx.y) {
    case 0:  src = s0; dst = d0; n4 = (BT * D_MODEL) / 4; break;
    case 1:  src = s1; dst = d1; n4 = (BT * D_MODEL) / 4; break;
    case 2:  src = s2; dst = d2; n4 = (BT * D_MODEL) / 4; break;
    case 3:  src = s3; dst = d3; n4 = (D_MODEL * D_MODEL) / 4; break;
    case 4:  src = s4; dst = d4; n4 = (D_MODEL * D_MODEL) / 4; break;
    case 5:  src = s5; dst = d5; n4 = (D_MODEL * D_MODEL) / 4; break;
    default: src = s6; dst = d6; n4 = (D_MODEL * D_MODEL) / 4; break;
  }
  int stride = gridDim.x * blockDim.x;
  for (int i = blockIdx.x * blockDim.x + threadIdx.x; i < n4; i += stride) {
    float4 f = ((const float4*)src)[i];
    bf16x4 h;
    h[0] = (bf16)f.x; h[1] = (bf16)f.y; h[2] = (bf16)f.z; h[3] = (bf16)f.w;
    ((bf16x4*)dst)[i] = h;
  }
}

// ---------------------------------------------------------------------------
// 128x128-tile GEMM core, K=1024, BK=32 (m97 structure, single-buffered:
// TLP across 3 blocks/CU hides staging latency; explicit dbuf regressed R11).
// ---------------------------------------------------------------------------
__device__ __forceinline__ void gemm128_core(
    const bf16* __restrict__ A, const bf16* __restrict__ W,
    int m0, int n0, bf16* As, bf16* Bs, floatx4 acc[4][4])
{
  const int t = threadIdx.x;
  const int l = t & 63, w = t >> 6;
  const int quad = l >> 4, lr = l & 15;
  const int wm = (w >> 1) * 64, wn = (w & 1) * 64;

  floatx4 z = {0.f, 0.f, 0.f, 0.f};
#pragma unroll
  for (int i = 0; i < 4; i++)
#pragma unroll
    for (int j = 0; j < 4; j++) acc[i][j] = z;

  for (int kt = 0; kt < 1024; kt += 32) {
    __syncthreads();
#pragma unroll
    for (int i = 0; i < 2; i++) {
      int c = i * 256 + t;
      int row = c >> 2, ci = c & 3;
      async_cp16(A + (size_t)(m0 + row) * 1024 + kt + ci * 8,
                 As + (i * 256 + w * 64) * 8);
      async_cp16(W + (size_t)(n0 + row) * 1024 + kt + ci * 8,
                 Bs + (i * 256 + w * 64) * 8);
    }
    __syncthreads();

    bf16x8 af[4], bfr[4];
#pragma unroll
    for (int i = 0; i < 4; i++) {
      af[i]  = *(const bf16x8*)(As + (wm + i * 16 + lr) * 32 + quad * 8);
      bfr[i] = *(const bf16x8*)(Bs + (wn + i * 16 + lr) * 32 + quad * 8);
    }
#pragma unroll
    for (int i = 0; i < 4; i++)
#pragma unroll
      for (int j = 0; j < 4; j++)
        acc[i][j] = MFMA16(af[i], bfr[j], acc[i][j]);
  }
}

// ---------------------------------------------------------------------------
// Fused QKV projection. zid selects (q,Wq)->qh, (k,Wk)->kh, (v,Wv)->vt.
// qh,kh: [B*H][T][64]; v stored TRANSPOSED [B*H][64][T].
// qh is pre-scaled by QSCALE (softmax scale folded + exp2 domain).
// ---------------------------------------------------------------------------
__global__ __launch_bounds__(256) void qkv_gemm(
    const bf16* __restrict__ qb, const bf16* __restrict__ kb, const bf16* __restrict__ vb,
    const bf16* __restrict__ wq, const bf16* __restrict__ wk, const bf16* __restrict__ wv,
    const float* __restrict__ biasq, const float* __restrict__ biask, const float* __restrict__ biasv,
    bf16* __restrict__ qh, bf16* __restrict__ kh, bf16* __restrict__ vt)
{
  __shared__ bf16 As[128 * 32];
  __shared__ bf16 Bs[128 * 32];
  const int zid = blockIdx.z;
  const bf16* A = (zid == 0) ? qb : ((zid == 1) ? kb : vb);
  const bf16* W = (zid == 0) ? wq : ((zid == 1) ? wk : wv);
  const float* bias = (zid == 0) ? biasq : ((zid == 1) ? biask : biasv);
  const int m0 = blockIdx.x * 128, n0 = blockIdx.y * 128;

  floatx4 acc[4][4];
  gemm128_core(A, W, m0, n0, As, Bs, acc);

  const int t = threadIdx.x, l = t & 63, w = t >> 6;
  const int quad = l >> 4, lr = l & 15;
  const int wm = (w >> 1) * 64, wn = (w & 1) * 64;
  const float sc = (zid == 0) ? QSCALE : 1.0f;

  if (zid < 2) {
    bf16* out = (zid == 0) ? qh : kh;
#pragma unroll
    for (int i = 0; i < 4; i++) {
      int mbase = m0 + wm + i * 16 + quad * 4;       // global row (b*2048+t)
      int b  = mbase >> 11;
      int tq = mbase & 2047;
#pragma unroll
      for (int j = 0; j < 4; j++) {
        int n = n0 + wn + j * 16 + lr;               // e = h*64 + dh
        float bv = bias[n];
        int h = n >> 6, dh = n & 63;
        bf16* p = out + ((size_t)((b * NHEAD + h) * SEQ + tq)) * HDIM + dh;
#pragma unroll
        for (int r = 0; r < 4; r++)
          p[(size_t)r * HDIM] = (bf16)((acc[i][j][r] + bv) * sc);
      }
    }
  } else {
#pragma unroll
    for (int i = 0; i < 4; i++) {
      int mbase = m0 + wm + i * 16 + quad * 4;
      int b  = mbase >> 11;
      int tq = mbase & 2047;
#pragma unroll
      for (int j = 0; j < 4; j++) {
        int n = n0 + wn + j * 16 + lr;
        float bv = bias[n];
        int h = n >> 6, dh = n & 63;
        bf16x4 pk;
#pragma unroll
        for (int r = 0; r < 4; r++) pk[r] = (bf16)(acc[i][j][r] + bv);
        *(bf16x4*)(vt + ((size_t)((b * NHEAD + h) * HDIM + dh)) * SEQ + tq) = pk;
      }
    }
  }
}

// ---------------------------------------------------------------------------
// Flash attention with register-carried PV overlap. Grid (T/128, B*H),
// block 256 = 4 waves; wave w owns q-rows qt0 + w*32 + {0..31} as TWO
// groups of 16 (g=0,1; q = g*16 + lr), all 128 keys of each tile.
// LDS (double-buffered, 2 x 32 KB):
//   K  [128 rows][64 el],  8-el chunk ci stored at physical ci ^ (row & 7)
//   V^T[ 64 rows][128 el], 8-el chunk ci stored at physical ci ^ (row & 15)
// Iteration t: barrier (tile t resident; buf (t-1)&1 free for overwrite);
// stage(t+1); QK(t) [32 MFMA]; PV(t-1) [40 MFMA from vreg+pk registers --
// overlaps SM(t)'s VALU on the other pipe]; SM(t) [writes pk(t)];
// VLOAD(t) [LDS V -> vreg for next iteration].
// Epilogue: PV(15) from regs; normalize by Racc[0]; LDS transpose; store.
// ---------------------------------------------------------------------------
__global__ __launch_bounds__(256, 2) void attn_fused(
    const bf16* __restrict__ qh, const bf16* __restrict__ kh,
    const bf16* __restrict__ vt, bf16* __restrict__ attn)
{
  __shared__ __align__(16) char smem[65536];   // 2 x (K 16KB + V 16KB)

  const int t = threadIdx.x, l = t & 63, w = t >> 6;   // w in 0..3
  const int quad = l >> 4, lr = l & 15;

  // XCD swizzle: linear block id % 8 = XCD. XCD x gets heads {x, x+8, x+16,
  // x+24}, all 16 q-tiles each: bijective over the 512-block grid.
  const int hb  = blockIdx.y * 16 + blockIdx.x;   // dispatch-linear id
  const int j   = hb >> 3;
  const int bh  = (hb & 7) + ((j & 3) << 3);
  const int qt0 = (j >> 2) * 128;

  const bf16* qg = qh + (size_t)bh * SEQ * HDIM;
  const bf16* kg = kh + (size_t)bh * SEQ * HDIM;
  const bf16* vg = vt + (size_t)bh * HDIM * SEQ;

  // Staging geometry (per wave, per tile): 4 K-segments + 4 V-segments,
  // segment index s = w*4 + i.
  // K seg s: rows s*8+(l>>3), phys chunk l&7  <- global chunk (l&7)^(row&7).
  // V seg s: rows s*4+(l>>4), phys chunk l&15 <- global chunk (l&15)^(row&15).
  const bf16* kseg[4];
  const bf16* vseg[4];
#pragma unroll
  for (int i = 0; i < 4; i++) {
    int s = w * 4 + i;
    int krow = s * 8 + (l >> 3);
    kseg[i] = kg + (size_t)krow * HDIM + (((l & 7) ^ (krow & 7)) * 8);
    int vrow = s * 4 + (l >> 4);
    vseg[i] = vg + (size_t)vrow * SEQ + (((l & 15) ^ (vrow & 15)) * 8);
  }

  // Q B-frags (K=32) for the wave's 32 q-rows: q = qt0 + w*32 + g*16 + lr.
  bf16x8 qf[2][2];
#pragma unroll
  for (int g = 0; g < 2; g++)
#pragma unroll
    for (int ko = 0; ko < 2; ko++)
      qf[g][ko] = *(const bf16x8*)(qg + (size_t)(qt0 + w * 32 + g * 16 + lr) * HDIM
                                   + ko * 32 + quad * 8);

  const floatx4 zz = {0.f, 0.f, 0.f, 0.f};
  floatx4 Oacc[2][4];   // [g] O^T[d = dt*16 + quad*4 + r][q = lr]
#pragma unroll
  for (int g = 0; g < 2; g++)
#pragma unroll
    for (int dt = 0; dt < 4; dt++) Oacc[g][dt] = zz;
  floatx4 Racc[2] = {zz, zz};   // rowsum(P) accum; all regs equal the sum
  float mrow[2] = {-3.0e38f, -3.0e38f};

  bf16x8 ones8;
#pragma unroll
  for (int i = 0; i < 8; i++) ones8[i] = (bf16)1.0f;

  auto stage = [&](int buf, int kt) {
    bf16* Kb = (bf16*)(smem + buf * 32768);
    bf16* Vb = (bf16*)(smem + buf * 32768 + 16384);
    int off = kt * 128;
#pragma unroll
    for (int i = 0; i < 4; i++) {
      async_cp16(kseg[i] + (size_t)off * HDIM, Kb + (w * 4 + i) * 512);
      async_cp16(vseg[i] + off,                Vb + (w * 4 + i) * 512);
    }
  };

  // QK for tile in buffer buf -> s0/s1 (lane: S[q=lr][key=ni*16+quad*4+r]).
  floatx4 s0[8], s1[8];
  auto QK = [&](int buf) {
    const bf16* Ks = (const bf16*)(smem + buf * 32768);
    const bf16* krow0 = Ks + lr * 64 + ((quad ^ (lr & 7)) * 8);
    const bf16* krow1 = Ks + lr * 64 + (((quad + 4) ^ (lr & 7)) * 8);
#pragma unroll
    for (int ni = 0; ni < 8; ni++) {
      bf16x8 k0 = *(const bf16x8*)(krow0 + ni * 1024);
      bf16x8 k1 = *(const bf16x8*)(krow1 + ni * 1024);
      floatx4 a0 = MFMA16(k0, qf[0][0], zz);
      floatx4 a1 = MFMA16(k0, qf[1][0], zz);
      a0 = MFMA16(k1, qf[0][1], a0);
      a1 = MFMA16(k1, qf[1][1], a1);
      s0[ni] = a0;
      s1[ni] = a1;
    }
  };

  // Softmax on s0/s1 -> pk (K=32 B-frags: pkg[nip][0..3] = keys 2nip*16+
  // quad*4+r, [4..7] = (2nip+1)*16+quad*4+r), updates mrow/Oacc/Racc.
  bf16x8 pk0[4], pk1[4];
  auto SM = [&]() {
#pragma unroll
    for (int g = 0; g < 2; g++) {
      floatx4* sg = g ? s1 : s0;
      bf16x8* pkg = g ? pk1 : pk0;

      float xm[8];
#pragma unroll
      for (int ni = 0; ni < 8; ni++) {
        float m01 = fmaxf(sg[ni][0], sg[ni][1]);
        xm[ni] = fmaxf(fmaxf(m01, sg[ni][2]), sg[ni][3]);   // max3-fusable
      }
      float rmax = fmaxf(fmaxf(xm[0], xm[1]), xm[2]);
      rmax = fmaxf(fmaxf(rmax, xm[3]), xm[4]);
      rmax = fmaxf(fmaxf(rmax, xm[5]), xm[6]);
      rmax = fmaxf(rmax, xm[7]);
      rmax = fmaxf(rmax, __shfl_xor(rmax, 16, 64));
      rmax = fmaxf(rmax, __shfl_xor(rmax, 32, 64));

      // defer-max (THR=8, exp2 domain): skip O/R rescale when no lane's max
      // grew by more than 8; P then bounded by 2^8, fp32 accum absorbs it.
      if (!__all(rmax - mrow[g] <= 8.0f)) {
        float mnew = fmaxf(mrow[g], rmax);
        float al = fexp2(mrow[g] - mnew);
        mrow[g] = mnew;
#pragma unroll
        for (int dt = 0; dt < 4; dt++)
#pragma unroll
          for (int r = 0; r < 4; r++) Oacc[g][dt][r] *= al;
#pragma unroll
        for (int r = 0; r < 4; r++) Racc[g][r] *= al;
      }

      const float m = mrow[g];
#pragma unroll
      for (int nip = 0; nip < 4; nip++) {
        bf16x8 pv;
#pragma unroll
        for (int r = 0; r < 4; r++) pv[r]     = (bf16)fexp2(sg[2*nip  ][r] - m);
#pragma unroll
        for (int r = 0; r < 4; r++) pv[4 + r] = (bf16)fexp2(sg[2*nip+1][r] - m);
        pkg[nip] = pv;
      }
    }
  };

  // V-fragment prefetch: LDS (buffer buf) -> vreg, for NEXT PV.
  // V logical chunks 4nip+(quad>>1) and 4nip+2+(quad>>1), phys = c ^ lr
  // (V row = dt*16+lr, row&15 == lr), sub-offset (quad&1)*4.
  bf16x8 vreg[4][4];
  auto VLOAD = [&](int buf) {
    const bf16* Vts = (const bf16*)(smem + buf * 32768 + 16384);
    const bf16* vbase = Vts + lr * 128 + (quad & 1) * 4;
#pragma unroll
    for (int nip = 0; nip < 4; nip++) {
      const bf16* vpA = vbase + ((((4 * nip)     + (quad >> 1)) ^ lr) * 8);
      const bf16* vpB = vbase + ((((4 * nip + 2) + (quad >> 1)) ^ lr) * 8);
#pragma unroll
      for (int dt = 0; dt < 4; dt++) {
        bf16x4 va = *(const bf16x4*)(vpA + dt * 2048);
        bf16x4 vb = *(const bf16x4*)(vpB + dt * 2048);
        vreg[nip][dt] = __builtin_shufflevector(va, vb, 0, 1, 2, 3, 4, 5, 6, 7);
      }
    }
  };

  // PV (K=32) for the tile whose P is in pk and V in vreg (pure register
  // MFMAs -- no LDS dependence; overlaps the following SM's VALU chain).
  auto PVR = [&]() {
#pragma unroll
    for (int nip = 0; nip < 4; nip++) {
      Racc[0] = MFMA16(ones8, pk0[nip], Racc[0]);
      Racc[1] = MFMA16(ones8, pk1[nip], Racc[1]);
#pragma unroll
      for (int dt = 0; dt < 4; dt++) {
        Oacc[0][dt] = MFMA16(vreg[nip][dt], pk0[nip], Oacc[0][dt]);
        Oacc[1][dt] = MFMA16(vreg[nip][dt], pk1[nip], Oacc[1][dt]);
      }
    }
  };

  // ---- Pipeline: PV lags one tile, carried in registers. ----
  stage(0, 0);
  __syncthreads();          // tile 0 resident
  stage(1, 1);
  QK(0);
  VLOAD(0);
  SM();                     // pk(0)
  for (int kt = 1; kt < 16; kt++) {
    __syncthreads();        // tile kt resident; buf (kt-1)&1 reads all done
    if (kt + 1 < 16) stage((kt + 1) & 1, kt + 1);
    QK(kt & 1);             // MFMA: S(kt)
    PVR();                  // MFMA: PV(kt-1) from regs -- overlaps SM below
    SM();                   // VALU: softmax(kt) -> pk(kt)
    VLOAD(kt & 1);          // LDS->reg: V(kt) for next iteration's PVR
  }
  PVR();                    // PV(15)

  // ---- Epilogue: normalize, transpose via LDS, coalesced store. ----
  // Ost overlays buf0 (tile 14: all reads done before barrier 15; lagging
  // waves in iter 15 touch only buf1, smem+32768..). 128*72*2B = 18KB.
  bf16* Ost = (bf16*)smem;
#pragma unroll
  for (int g = 0; g < 2; g++) {
    float inv = 1.0f / Racc[g][0];
#pragma unroll
    for (int dt = 0; dt < 4; dt++) {
      bf16x4 ov;
#pragma unroll
      for (int r = 0; r < 4; r++) ov[r] = (bf16)(Oacc[g][dt][r] * inv);
      *(bf16x4*)(Ost + (size_t)(w * 32 + g * 16 + lr) * 72 + dt * 16 + quad * 4) = ov;
    }
  }
  __syncthreads();

  // stream Ost [128 q][64 d] to attn[b][qt0+row][h*64 + d], coalesced 16B.
  const int b = bh >> 4, h = bh & 15;
#pragma unroll
  for (int i = 0; i < 4; i++) {
    int c = t + 256 * i;
    int row = c >> 3, ci = c & 7;
    *(int4*)(attn + ((size_t)b * SEQ + qt0 + row) * D_MODEL + h * HDIM + ci * 8) =
        *(const int4*)(Ost + row * 72 + ci * 8);
  }
}

// ---------------------------------------------------------------------------
// Output projection: out = attn @ Wo^T + bo, fp32 output.
// 128x64 tiles, single-buffered (R10 structure). Grid (32,16) = 512 blocks.
// ---------------------------------------------------------------------------
__global__ __launch_bounds__(256) void oproj_gemm(
    const bf16* __restrict__ attn, const bf16* __restrict__ wo,
    const float* __restrict__ bo, float* __restrict__ out)
{
  __shared__ bf16 As[128 * 32];   // 8KB
  __shared__ bf16 Bs[64 * 32];    // 4KB
  const int m0 = blockIdx.x * 128, n0 = blockIdx.y * 64;
  const int t = threadIdx.x, l = t & 63, w = t >> 6;
  const int quad = l >> 4, lr = l & 15;
  const int wm = (w >> 1) * 64, wn = (w & 1) * 32;

  floatx4 z = {0.f, 0.f, 0.f, 0.f};
  floatx4 acc[4][2];
#pragma unroll
  for (int i = 0; i < 4; i++)
#pragma unroll
    for (int j = 0; j < 2; j++) acc[i][j] = z;

  for (int kt = 0; kt < 1024; kt += 32) {
    __syncthreads();
#pragma unroll
    for (int i = 0; i < 2; i++) {
      int c = i * 256 + t;
      int row = c >> 2, ci = c & 3;          // A: 128 rows x 4 chunks
      async_cp16(attn + (size_t)(m0 + row) * 1024 + kt + ci * 8,
                 As + (i * 256 + w * 64) * 8);
    }
    {
      int row = t >> 2, ci = t & 3;          // B: 64 rows x 4 chunks
      async_cp16(wo + (size_t)(n0 + row) * 1024 + kt + ci * 8,
                 Bs + (w * 64) * 8);
    }
    __syncthreads();

    bf16x8 af[4], bfr[2];
#pragma unroll
    for (int i = 0; i < 4; i++)
      af[i]  = *(const bf16x8*)(As + (wm + i * 16 + lr) * 32 + quad * 8);
#pragma unroll
    for (int j = 0; j < 2; j++)
      bfr[j] = *(const bf16x8*)(Bs + (wn + j * 16 + lr) * 32 + quad * 8);
#pragma unroll
    for (int i = 0; i < 4; i++)
#pragma unroll
      for (int j = 0; j < 2; j++)
        acc[i][j] = MFMA16(af[i], bfr[j], acc[i][j]);
  }

#pragma unroll
  for (int i = 0; i < 4; i++) {
    int m = m0 + wm + i * 16 + quad * 4;
#pragma unroll
    for (int j = 0; j < 2; j++) {
      int n = n0 + wn + j * 16 + lr;
      float bv = bo[n];
      float* p = out + (size_t)m * D_MODEL + n;
#pragma unroll
      for (int r = 0; r < 4; r++)
        p[(size_t)r * D_MODEL] = acc[i][j][r] + bv;
    }
  }
}

// ---------------------------------------------------------------------------
extern "C" void kernel_launch(void* const* d_in, const int* in_sizes, int n_in,
                              void* d_out, int out_size, void* d_ws, size_t ws_size,
                              hipStream_t stream)
{
  const float* q  = (const float*)d_in[0];
  const float* k  = (const float*)d_in[1];
  const float* v  = (const float*)d_in[2];
  const float* Wq = (const float*)d_in[3];
  const float* bq = (const float*)d_in[4];
  const float* Wk = (const float*)d_in[5];
  const float* bk = (const float*)d_in[6];
  const float* Wv = (const float*)d_in[7];
  const float* bv = (const float*)d_in[8];
  const float* Wo = (const float*)d_in[9];
  const float* bo = (const float*)d_in[10];

  const size_t NQ = (size_t)BT * D_MODEL;        // 4194304
  const size_t NW = (size_t)D_MODEL * D_MODEL;   // 1048576

  bf16* p = (bf16*)d_ws;
  bf16* qb   = p; p += NQ;
  bf16* kb   = p; p += NQ;
  bf16* vb   = p; p += NQ;
  bf16* wqb  = p; p += NW;
  bf16* wkb  = p; p += NW;
  bf16* wvb  = p; p += NW;
  bf16* wob  = p; p += NW;
  bf16* qhp  = p; p += NQ;   // [B*H][T][64], pre-scaled by QSCALE
  bf16* khp  = p; p += NQ;   // [B*H][T][64]
  bf16* vtp  = p; p += NQ;   // [B*H][64][T]
  bf16* attn = p; p += NQ;   // [B][T][1024]

  cvt7<<<dim3(1024, 7, 1), 256, 0, stream>>>(q, k, v, Wq, Wk, Wv, Wo,
                                             qb, kb, vb, wqb, wkb, wvb, wob);
  qkv_gemm<<<dim3(32, 8, 3), 256, 0, stream>>>(qb, kb, vb, wqb, wkb, wvb,
                                               bq, bk, bv, qhp, khp, vtp);
  attn_fused<<<dim3(16, 32, 1), 256, 0, stream>>>(qhp, khp, vtp, attn);
  oproj_gemm<<<dim3(32, 16, 1), 256, 0, stream>>>(attn, wob, bo, (float*)d_out);
}

// Round 10
// 217.381 us; speedup vs baseline: 1.0276x; 1.0276x over previous
//
#include <hip/hip_runtime.h>
#include <cstdint>
#include <cstddef>

// ---------------------------------------------------------------------------
// MultiHeadAttention forward, MI355X/gfx950.
// cvt(fp32->bf16) -> fused QKV GEMM (MFMA) -> flash attention -> out-proj.
// MFMA layouts (m89/m91/m120):
//   K=32 A-frag: lane l holds A[m=l&15][k=(l>>4)*8+j], j=0..7
//   K=32 B-frag: lane l holds Bt[n=l&15][k=(l>>4)*8+j]
//   C/D: lane l, reg r holds D[m=(l>>4)*4+r][n=l&15]
// R16: revert attn to R13 geometry (best: 53.9us) + fine-grained SM/PV
// interleave. Post-mortems: R14b's offset pipeline doubled barriers
// (53.9->61.4); R15's register-carried variant spilled (WRITE_SIZE
// 8192->14848KB, +6.6MB scratch; 53.9->63.4). Lesson: the PV/SM overlap
// must be FREE -- no extra barriers, no state across barriers. R16 keeps
// R13's KVBLK=128 / 2 buffers / 16 barriers and only reorders the tile
// body: {rmax+rescale} then per-nip {V-frag ds_reads -> 16 exp2+pack
// (covers ds latency) -> 10 MFMAs}. Each nip's MFMAs depend only on its
// own pk, so the scheduler overlaps nip+1's VALU with nip's MFMAs inside
// one basic block (R13's monolithic 64-exp2-then-40-MFMA phases likely
// exceeded its window; MfmaUtil was 27.5%). pk becomes a per-nip local
// (was 32 persistent VGPRs) -> pressure drops vs R13.
// Kept: 4 waves x 32 q (2 groups of 16) sharing K LDS reads, XCD swizzle,
// XOR-swizzled unpadded K/V LDS, ones-MFMA Racc rowsum, K=32 PV, max3-tree
// rmax, defer-max THR=8, exp2 domain (QSCALE folded), separate cvt7 (R12
// falsified fusion), single-buffered projection GEMMs (R11 falsified dbuf).
// ---------------------------------------------------------------------------

#define D_MODEL 1024
#define NHEAD   16
#define HDIM    64
#define BATCH   2
#define SEQ     2048
#define BT      (BATCH * SEQ)   // 4096

// (1/sqrt(HDIM)) * log2(e) -- folds softmax scale + exp->exp2 conversion
#define QSCALE 0.18033688011112043f

typedef __bf16 bf16;
typedef __bf16 bf16x8 __attribute__((ext_vector_type(8)));
typedef __bf16 bf16x4 __attribute__((ext_vector_type(4)));
typedef float  floatx4 __attribute__((ext_vector_type(4)));
typedef short  short4v __attribute__((ext_vector_type(4)));

#define MFMA16(a, b, c) __builtin_amdgcn_mfma_f32_16x16x32_bf16((a), (b), (c), 0, 0, 0)

__device__ __forceinline__ float fexp2(float x) {
  return __builtin_amdgcn_exp2f(x);   // v_exp_f32: D = 2^S0
}

// async global->LDS, 16B per lane. LDS dest = wave-uniform base + lane*16.
__device__ __forceinline__ void async_cp16(const bf16* g, bf16* l) {
  __builtin_amdgcn_global_load_lds(
      (__attribute__((address_space(1))) void*)(g),
      (__attribute__((address_space(3))) void*)(l), 16, 0, 0);
}

// ---------------------------------------------------------------------------
// fp32 -> bf16 conversion for q,k,v and the 4 weight matrices.
// ---------------------------------------------------------------------------
__global__ __launch_bounds__(256) void cvt7(
    const float* __restrict__ s0, const float* __restrict__ s1,
    const float* __restrict__ s2, const float* __restrict__ s3,
    const float* __restrict__ s4, const float* __restrict__ s5,
    const float* __restrict__ s6,
    bf16* __restrict__ d0, bf16* __restrict__ d1, bf16* __restrict__ d2,
    bf16* __restrict__ d3, bf16* __restrict__ d4, bf16* __restrict__ d5,
    bf16* __restrict__ d6)
{
  const float* src; bf16* dst; int n4;
  switch (blockIdx.y) {
    case 0:  src = s0; dst = d0; n4 = (BT * D_MODEL) / 4; break;
    case 1:  src = s1; dst = d1; n4 = (BT * D_MODEL) / 4; break;
    case 2:  src = s2; dst = d2; n4 = (BT * D_MODEL) / 4; break;
    case 3:  src = s3; dst = d3; n4 = (D_MODEL * D_MODEL) / 4; break;
    case 4:  src = s4; dst = d4; n4 = (D_MODEL * D_MODEL) / 4; break;
    case 5:  src = s5; dst = d5; n4 = (D_MODEL * D_MODEL) / 4; break;
    default: src = s6; dst = d6; n4 = (D_MODEL * D_MODEL) / 4; break;
  }
  int stride = gridDim.x * blockDim.x;
  for (int i = blockIdx.x * blockDim.x + threadIdx.x; i < n4; i += stride) {
    float4 f = ((const float4*)src)[i];
    bf16x4 h;
    h[0] = (bf16)f.x; h[1] = (bf16)f.y; h[2] = (bf16)f.z; h[3] = (bf16)f.w;
    ((bf16x4*)dst)[i] = h;
  }
}

// ---------------------------------------------------------------------------
// 128x128-tile GEMM core, K=1024, BK=32 (m97 structure, single-buffered:
// TLP across 3 blocks/CU hides staging latency; explicit dbuf regressed R11).
// ---------------------------------------------------------------------------
__device__ __forceinline__ void gemm128_core(
    const bf16* __restrict__ A, const bf16* __restrict__ W,
    int m0, int n0, bf16* As, bf16* Bs, floatx4 acc[4][4])
{
  const int t = threadIdx.x;
  const int l = t & 63, w = t >> 6;
  const int quad = l >> 4, lr = l & 15;
  const int wm = (w >> 1) * 64, wn = (w & 1) * 64;

  floatx4 z = {0.f, 0.f, 0.f, 0.f};
#pragma unroll
  for (int i = 0; i < 4; i++)
#pragma unroll
    for (int j = 0; j < 4; j++) acc[i][j] = z;

  for (int kt = 0; kt < 1024; kt += 32) {
    __syncthreads();
#pragma unroll
    for (int i = 0; i < 2; i++) {
      int c = i * 256 + t;
      int row = c >> 2, ci = c & 3;
      async_cp16(A + (size_t)(m0 + row) * 1024 + kt + ci * 8,
                 As + (i * 256 + w * 64) * 8);
      async_cp16(W + (size_t)(n0 + row) * 1024 + kt + ci * 8,
                 Bs + (i * 256 + w * 64) * 8);
    }
    __syncthreads();

    bf16x8 af[4], bfr[4];
#pragma unroll
    for (int i = 0; i < 4; i++) {
      af[i]  = *(const bf16x8*)(As + (wm + i * 16 + lr) * 32 + quad * 8);
      bfr[i] = *(const bf16x8*)(Bs + (wn + i * 16 + lr) * 32 + quad * 8);
    }
#pragma unroll
    for (int i = 0; i < 4; i++)
#pragma unroll
      for (int j = 0; j < 4; j++)
        acc[i][j] = MFMA16(af[i], bfr[j], acc[i][j]);
  }
}

// ---------------------------------------------------------------------------
// Fused QKV projection. zid selects (q,Wq)->qh, (k,Wk)->kh, (v,Wv)->vt.
// qh,kh: [B*H][T][64]; v stored TRANSPOSED [B*H][64][T].
// qh is pre-scaled by QSCALE (softmax scale folded + exp2 domain).
// ---------------------------------------------------------------------------
__global__ __launch_bounds__(256) void qkv_gemm(
    const bf16* __restrict__ qb, const bf16* __restrict__ kb, const bf16* __restrict__ vb,
    const bf16* __restrict__ wq, const bf16* __restrict__ wk, const bf16* __restrict__ wv,
    const float* __restrict__ biasq, const float* __restrict__ biask, const float* __restrict__ biasv,
    bf16* __restrict__ qh, bf16* __restrict__ kh, bf16* __restrict__ vt)
{
  __shared__ bf16 As[128 * 32];
  __shared__ bf16 Bs[128 * 32];
  const int zid = blockIdx.z;
  const bf16* A = (zid == 0) ? qb : ((zid == 1) ? kb : vb);
  const bf16* W = (zid == 0) ? wq : ((zid == 1) ? wk : wv);
  const float* bias = (zid == 0) ? biasq : ((zid == 1) ? biask : biasv);
  const int m0 = blockIdx.x * 128, n0 = blockIdx.y * 128;

  floatx4 acc[4][4];
  gemm128_core(A, W, m0, n0, As, Bs, acc);

  const int t = threadIdx.x, l = t & 63, w = t >> 6;
  const int quad = l >> 4, lr = l & 15;
  const int wm = (w >> 1) * 64, wn = (w & 1) * 64;
  const float sc = (zid == 0) ? QSCALE : 1.0f;

  if (zid < 2) {
    bf16* out = (zid == 0) ? qh : kh;
#pragma unroll
    for (int i = 0; i < 4; i++) {
      int mbase = m0 + wm + i * 16 + quad * 4;       // global row (b*2048+t)
      int b  = mbase >> 11;
      int tq = mbase & 2047;
#pragma unroll
      for (int j = 0; j < 4; j++) {
        int n = n0 + wn + j * 16 + lr;               // e = h*64 + dh
        float bv = bias[n];
        int h = n >> 6, dh = n & 63;
        bf16* p = out + ((size_t)((b * NHEAD + h) * SEQ + tq)) * HDIM + dh;
#pragma unroll
        for (int r = 0; r < 4; r++)
          p[(size_t)r * HDIM] = (bf16)((acc[i][j][r] + bv) * sc);
      }
    }
  } else {
#pragma unroll
    for (int i = 0; i < 4; i++) {
      int mbase = m0 + wm + i * 16 + quad * 4;
      int b  = mbase >> 11;
      int tq = mbase & 2047;
#pragma unroll
      for (int j = 0; j < 4; j++) {
        int n = n0 + wn + j * 16 + lr;
        float bv = bias[n];
        int h = n >> 6, dh = n & 63;
        bf16x4 pk;
#pragma unroll
        for (int r = 0; r < 4; r++) pk[r] = (bf16)(acc[i][j][r] + bv);
        *(bf16x4*)(vt + ((size_t)((b * NHEAD + h) * HDIM + dh)) * SEQ + tq) = pk;
      }
    }
  }
}

// ---------------------------------------------------------------------------
// Flash attention. Grid (T/128, B*H), block 256 = 4 waves; wave w owns
// q-rows qt0 + w*32 + {0..31} as TWO groups of 16 (g=0,1; q = g*16 + lr),
// all 128 keys of each tile. Every K-frag / V-frag LDS read feeds BOTH
// groups' MFMAs. Block ids are XCD-swizzled so the 16 q-tile blocks of a
// given bh (+3 more bh) share one XCD's L2 (K/V working set 3MB < 4MB).
// LDS (double-buffered, 2 x 32 KB):
//   K  [128 rows][64 el],  8-el chunk ci stored at physical ci ^ (row & 7)
//   V^T[ 64 rows][128 el], 8-el chunk ci stored at physical ci ^ (row & 15)
// Staged via global_load_lds; one barrier per tile (stage k+1 after
// barrier k). Tile body: QK (32 MFMA) -> rmax+rescale (serial head) ->
// per-nip fused {V ds_reads -> 16 exp2+pack -> 10 MFMAs} so nip+1's VALU
// overlaps nip's MFMAs in the scheduler window.
// Epilogue: normalize by Racc[0], LDS transpose ([128][72] overlay), store.
// ---------------------------------------------------------------------------
__global__ __launch_bounds__(256, 2) void attn_fused(
    const bf16* __restrict__ qh, const bf16* __restrict__ kh,
    const bf16* __restrict__ vt, bf16* __restrict__ attn)
{
  __shared__ __align__(16) char smem[65536];   // 2 x (K 16KB + V 16KB)

  const int t = threadIdx.x, l = t & 63, w = t >> 6;   // w in 0..3
  const int quad = l >> 4, lr = l & 15;

  // XCD swizzle: linear block id % 8 = XCD. XCD x gets heads {x, x+8, x+16,
  // x+24}, all 16 q-tiles each: bijective over the 512-block grid.
  const int hb  = blockIdx.y * 16 + blockIdx.x;   // dispatch-linear id
  const int j   = hb >> 3;
  const int bh  = (hb & 7) + ((j & 3) << 3);
  const int qt0 = (j >> 2) * 128;

  const bf16* qg = qh + (size_t)bh * SEQ * HDIM;
  const bf16* kg = kh + (size_t)bh * SEQ * HDIM;
  const bf16* vg = vt + (size_t)bh * HDIM * SEQ;

  // Staging geometry (per wave, per tile): 4 K-segments + 4 V-segments,
  // segment index s = w*4 + i.
  // K seg s: rows s*8+(l>>3), phys chunk l&7  <- global chunk (l&7)^(row&7).
  // V seg s: rows s*4+(l>>4), phys chunk l&15 <- global chunk (l&15)^(row&15).
  const bf16* kseg[4];
  const bf16* vseg[4];
#pragma unroll
  for (int i = 0; i < 4; i++) {
    int s = w * 4 + i;
    int krow = s * 8 + (l >> 3);
    kseg[i] = kg + (size_t)krow * HDIM + (((l & 7) ^ (krow & 7)) * 8);
    int vrow = s * 4 + (l >> 4);
    vseg[i] = vg + (size_t)vrow * SEQ + (((l & 15) ^ (vrow & 15)) * 8);
  }

  // Q B-frags (K=32) for the wave's 32 q-rows: q = qt0 + w*32 + g*16 + lr.
  bf16x8 qf[2][2];
#pragma unroll
  for (int g = 0; g < 2; g++)
#pragma unroll
    for (int ko = 0; ko < 2; ko++)
      qf[g][ko] = *(const bf16x8*)(qg + (size_t)(qt0 + w * 32 + g * 16 + lr) * HDIM
                                   + ko * 32 + quad * 8);

  const floatx4 zz = {0.f, 0.f, 0.f, 0.f};
  floatx4 Oacc[2][4];   // [g] O^T[d = dt*16 + quad*4 + r][q = lr]
#pragma unroll
  for (int g = 0; g < 2; g++)
#pragma unroll
    for (int dt = 0; dt < 4; dt++) Oacc[g][dt] = zz;
  floatx4 Racc[2] = {zz, zz};   // rowsum(P) accum; all regs equal the sum
  float mrow[2] = {-3.0e38f, -3.0e38f};

  bf16x8 ones8;
#pragma unroll
  for (int i = 0; i < 8; i++) ones8[i] = (bf16)1.0f;

  auto stage = [&](int buf, int kt) {
    bf16* Kb = (bf16*)(smem + buf * 32768);
    bf16* Vb = (bf16*)(smem + buf * 32768 + 16384);
    int off = kt * 128;
#pragma unroll
    for (int i = 0; i < 4; i++) {
      async_cp16(kseg[i] + (size_t)off * HDIM, Kb + (w * 4 + i) * 512);
      async_cp16(vseg[i] + off,                Vb + (w * 4 + i) * 512);
    }
  };

  // prologue: stage tile 0 into buffer 0
  stage(0, 0);

  for (int kt = 0; kt < 16; kt++) {
    const int p = kt & 1;
    __syncthreads();   // drains vmcnt -> tile kt resident in buf p;
                       // all waves done reading buf 1-p (tile kt-1)
    if (kt + 1 < 16) stage(1 - p, kt + 1);
    const bf16* Ks  = (const bf16*)(smem + p * 32768);
    const bf16* Vts = (const bf16*)(smem + p * 32768 + 16384);

    // K A-frag bases are lane-constant; per-ni reads use immediate offsets.
    const bf16* krow0 = Ks + lr * 64 + ((quad ^ (lr & 7)) * 8);
    const bf16* krow1 = Ks + lr * 64 + (((quad + 4) ^ (lr & 7)) * 8);

    // S^T per group: lane holds S[q=lr][key = ni*16 + quad*4 + r], ni=0..7.
    // Each K-frag pair (k0,k1) is read ONCE and feeds both groups.
    floatx4 s0[8], s1[8];
#pragma unroll
    for (int ni = 0; ni < 8; ni++) {
      bf16x8 k0 = *(const bf16x8*)(krow0 + ni * 1024);
      bf16x8 k1 = *(const bf16x8*)(krow1 + ni * 1024);
      floatx4 a0 = MFMA16(k0, qf[0][0], zz);
      floatx4 a1 = MFMA16(k0, qf[1][0], zz);
      a0 = MFMA16(k1, qf[0][1], a0);
      a1 = MFMA16(k1, qf[1][1], a1);
      s0[ni] = a0;
      s1[ni] = a1;
    }

    // ---- Serial head: rmax (max3-tree) + defer-max rescale, both groups.
#pragma unroll
    for (int g = 0; g < 2; g++) {
      floatx4* sg = g ? s1 : s0;
      float xm[8];
#pragma unroll
      for (int ni = 0; ni < 8; ni++) {
        float m01 = fmaxf(sg[ni][0], sg[ni][1]);
        xm[ni] = fmaxf(fmaxf(m01, sg[ni][2]), sg[ni][3]);   // max3-fusable
      }
      float rmax = fmaxf(fmaxf(xm[0], xm[1]), xm[2]);
      rmax = fmaxf(fmaxf(rmax, xm[3]), xm[4]);
      rmax = fmaxf(fmaxf(rmax, xm[5]), xm[6]);
      rmax = fmaxf(rmax, xm[7]);
      rmax = fmaxf(rmax, __shfl_xor(rmax, 16, 64));
      rmax = fmaxf(rmax, __shfl_xor(rmax, 32, 64));

      // defer-max (THR=8, exp2 domain): skip O/R rescale when no lane's max
      // grew by more than 8; P then bounded by 2^8, fp32 accum absorbs it.
      if (!__all(rmax - mrow[g] <= 8.0f)) {
        float mnew = fmaxf(mrow[g], rmax);
        float al = fexp2(mrow[g] - mnew);
        mrow[g] = mnew;
#pragma unroll
        for (int dt = 0; dt < 4; dt++)
#pragma unroll
          for (int r = 0; r < 4; r++) Oacc[g][dt][r] *= al;
#pragma unroll
        for (int r = 0; r < 4; r++) Racc[g][r] *= al;
      }
    }
    const float m0v = mrow[0], m1v = mrow[1];

    // ---- Fused per-nip SM+PV: {V ds_reads -> exp2+pack -> 10 MFMAs}.
    // V logical chunks 4nip+(quad>>1), 4nip+2+(quad>>1); phys = c ^ lr
    // (V row = dt*16+lr, row&15 == lr); sub-offset (quad&1)*4. K=32 PV:
    // pv[0..3] = keys 2nip*16+quad*4+r, pv[4..7] = (2nip+1)*16+quad*4+r.
    const bf16* vbase = Vts + lr * 128 + (quad & 1) * 4;
#pragma unroll
    for (int nip = 0; nip < 4; nip++) {
      // V-frag loads first: ds_read latency hides under the exp2 chain.
      const bf16* vpA = vbase + ((((4 * nip)     + (quad >> 1)) ^ lr) * 8);
      const bf16* vpB = vbase + ((((4 * nip + 2) + (quad >> 1)) ^ lr) * 8);
      bf16x8 vf[4];
#pragma unroll
      for (int dt = 0; dt < 4; dt++) {
        bf16x4 va = *(const bf16x4*)(vpA + dt * 2048);
        bf16x4 vb = *(const bf16x4*)(vpB + dt * 2048);
        vf[dt] = __builtin_shufflevector(va, vb, 0, 1, 2, 3, 4, 5, 6, 7);
      }
      // P fragments for this nip (local; freed after the MFMAs below).
      bf16x8 pv0, pv1;
#pragma unroll
      for (int r = 0; r < 4; r++) {
        pv0[r]     = (bf16)fexp2(s0[2*nip  ][r] - m0v);
        pv0[4 + r] = (bf16)fexp2(s0[2*nip+1][r] - m0v);
        pv1[r]     = (bf16)fexp2(s1[2*nip  ][r] - m1v);
        pv1[4 + r] = (bf16)fexp2(s1[2*nip+1][r] - m1v);
      }
      // MFMAs for this nip; next nip's loads/exp2 overlap these.
      Racc[0] = MFMA16(ones8, pv0, Racc[0]);
      Racc[1] = MFMA16(ones8, pv1, Racc[1]);
#pragma unroll
      for (int dt = 0; dt < 4; dt++) {
        Oacc[0][dt] = MFMA16(vf[dt], pv0, Oacc[0][dt]);
        Oacc[1][dt] = MFMA16(vf[dt], pv1, Oacc[1][dt]);
      }
    }
  }

  // ---- Epilogue: normalize, transpose via LDS, coalesced store. ----
  // Buffer 0 was last read at tile 14; all waves are past the tile-15
  // barrier, so it is free for the Ost overlay ([128][72] padded, 18KB).
  bf16* Ost = (bf16*)smem;
#pragma unroll
  for (int g = 0; g < 2; g++) {
    float inv = 1.0f / Racc[g][0];
#pragma unroll
    for (int dt = 0; dt < 4; dt++) {
      bf16x4 ov;
#pragma unroll
      for (int r = 0; r < 4; r++) ov[r] = (bf16)(Oacc[g][dt][r] * inv);
      *(bf16x4*)(Ost + (size_t)(w * 32 + g * 16 + lr) * 72 + dt * 16 + quad * 4) = ov;
    }
  }
  __syncthreads();

  // stream Ost [128 q][64 d] to attn[b][qt0+row][h*64 + d], coalesced 16B.
  const int b = bh >> 4, h = bh & 15;
#pragma unroll
  for (int i = 0; i < 4; i++) {
    int c = t + 256 * i;
    int row = c >> 3, ci = c & 7;
    *(int4*)(attn + ((size_t)b * SEQ + qt0 + row) * D_MODEL + h * HDIM + ci * 8) =
        *(const int4*)(Ost + row * 72 + ci * 8);
  }
}

// ---------------------------------------------------------------------------
// Output projection: out = attn @ Wo^T + bo, fp32 output.
// 128x64 tiles, single-buffered (R10 structure). Grid (32,16) = 512 blocks.
// ---------------------------------------------------------------------------
__global__ __launch_bounds__(256) void oproj_gemm(
    const bf16* __restrict__ attn, const bf16* __restrict__ wo,
    const float* __restrict__ bo, float* __restrict__ out)
{
  __shared__ bf16 As[128 * 32];   // 8KB
  __shared__ bf16 Bs[64 * 32];    // 4KB
  const int m0 = blockIdx.x * 128, n0 = blockIdx.y * 64;
  const int t = threadIdx.x, l = t & 63, w = t >> 6;
  const int quad = l >> 4, lr = l & 15;
  const int wm = (w >> 1) * 64, wn = (w & 1) * 32;

  floatx4 z = {0.f, 0.f, 0.f, 0.f};
  floatx4 acc[4][2];
#pragma unroll
  for (int i = 0; i < 4; i++)
#pragma unroll
    for (int j = 0; j < 2; j++) acc[i][j] = z;

  for (int kt = 0; kt < 1024; kt += 32) {
    __syncthreads();
#pragma unroll
    for (int i = 0; i < 2; i++) {
      int c = i * 256 + t;
      int row = c >> 2, ci = c & 3;          // A: 128 rows x 4 chunks
      async_cp16(attn + (size_t)(m0 + row) * 1024 + kt + ci * 8,
                 As + (i * 256 + w * 64) * 8);
    }
    {
      int row = t >> 2, ci = t & 3;          // B: 64 rows x 4 chunks
      async_cp16(wo + (size_t)(n0 + row) * 1024 + kt + ci * 8,
                 Bs + (w * 64) * 8);
    }
    __syncthreads();

    bf16x8 af[4], bfr[2];
#pragma unroll
    for (int i = 0; i < 4; i++)
      af[i]  = *(const bf16x8*)(As + (wm + i * 16 + lr) * 32 + quad * 8);
#pragma unroll
    for (int j = 0; j < 2; j++)
      bfr[j] = *(const bf16x8*)(Bs + (wn + j * 16 + lr) * 32 + quad * 8);
#pragma unroll
    for (int i = 0; i < 4; i++)
#pragma unroll
      for (int j = 0; j < 2; j++)
        acc[i][j] = MFMA16(af[i], bfr[j], acc[i][j]);
  }

#pragma unroll
  for (int i = 0; i < 4; i++) {
    int m = m0 + wm + i * 16 + quad * 4;
#pragma unroll
    for (int j = 0; j < 2; j++) {
      int n = n0 + wn + j * 16 + lr;
      float bv = bo[n];
      float* p = out + (size_t)m * D_MODEL + n;
#pragma unroll
      for (int r = 0; r < 4; r++)
        p[(size_t)r * D_MODEL] = acc[i][j][r] + bv;
    }
  }
}

// ---------------------------------------------------------------------------
extern "C" void kernel_launch(void* const* d_in, const int* in_sizes, int n_in,
                              void* d_out, int out_size, void* d_ws, size_t ws_size,
                              hipStream_t stream)
{
  const float* q  = (const float*)d_in[0];
  const float* k  = (const float*)d_in[1];
  const float* v  = (const float*)d_in[2];
  const float* Wq = (const float*)d_in[3];
  const float* bq = (const float*)d_in[4];
  const float* Wk = (const float*)d_in[5];
  const float* bk = (const float*)d_in[6];
  const float* Wv = (const float*)d_in[7];
  const float* bv = (const float*)d_in[8];
  const float* Wo = (const float*)d_in[9];
  const float* bo = (const float*)d_in[10];

  const size_t NQ = (size_t)BT * D_MODEL;        // 4194304
  const size_t NW = (size_t)D_MODEL * D_MODEL;   // 1048576

  bf16* p = (bf16*)d_ws;
  bf16* qb   = p; p += NQ;
  bf16* kb   = p; p += NQ;
  bf16* vb   = p; p += NQ;
  bf16* wqb  = p; p += NW;
  bf16* wkb  = p; p += NW;
  bf16* wvb  = p; p += NW;
  bf16* wob  = p; p += NW;
  bf16* qhp  = p; p += NQ;   // [B*H][T][64], pre-scaled by QSCALE
  bf16* khp  = p; p += NQ;   // [B*H][T][64]
  bf16* vtp  = p; p += NQ;   // [B*H][64][T]
  bf16* attn = p; p += NQ;   // [B][T][1024]

  cvt7<<<dim3(1024, 7, 1), 256, 0, stream>>>(q, k, v, Wq, Wk, Wv, Wo,
                                             qb, kb, vb, wqb, wkb, wvb, wob);
  qkv_gemm<<<dim3(32, 8, 3), 256, 0, stream>>>(qb, kb, vb, wqb, wkb, wvb,
                                               bq, bk, bv, qhp, khp, vtp);
  attn_fused<<<dim3(16, 32, 1), 256, 0, stream>>>(qhp, khp, vtp, attn);
  oproj_gemm<<<dim3(32, 16, 1), 256, 0, stream>>>(attn, wob, bo, (float*)d_out);
}